// Round 8
// baseline (54.801 us; speedup 1.0000x reference)
//
#include <hip/hip_runtime.h>
#include <math.h>

#define B_TOT 1024
#define IN_N  128
#define IN_D  16
#define NCAP  32
#define DCAP  32

typedef __attribute__((ext_vector_type(8)))  short bf16x8;
typedef __attribute__((ext_vector_type(16))) float f32x16;
typedef unsigned int  uint_;
typedef unsigned short ushort_;

__device__ __forceinline__ uint_ cvt_pk_bf16(float lo, float hi) {
    uint_ r;
    asm("v_cvt_pk_bf16_f32 %0, %1, %2" : "=v"(r) : "v"(lo), "v"(hi));
    return r;
}
__device__ __forceinline__ float bf16_to_f(ushort_ h) {
    return __uint_as_float(((uint_)h) << 16);
}

// ---------------------------------------------------------------------------
// prep (fused): blocks [0,512): W[n][j][i][z] -> WT[((n*128+j)*32+z)*16+i] bf16
//               blocks [512,1024): x transpose -> XW[(j*2+ib)*1024+b][8] bf16
// prep_x uses an XOR-swizzled LDS tile (8B units, unit ^= row&15): both the
// write (one 8B store/lane) and read (two 8B loads/lane) are conflict-free.
// ---------------------------------------------------------------------------
__global__ __launch_bounds__(256)
void prep(const float* __restrict__ x, const float* __restrict__ W,
          ushort_* __restrict__ XW, ushort_* __restrict__ WT) {
    const int blk = blockIdx.x;
    const int t   = threadIdx.x;

    if (blk < 512) {
        const int q  = blk * 256 + t;       // 131072 = 32n*128j*32z
        const int z  = q & 31;
        const int nj = q >> 5;
        const float* p = W + (size_t)nj * (IN_D * DCAP) + z;
        float f[16];
#pragma unroll
        for (int i = 0; i < 16; ++i) f[i] = p[i * 32];
        uint4 lo, hi;
        lo.x = cvt_pk_bf16(f[0],  f[1]);  lo.y = cvt_pk_bf16(f[2],  f[3]);
        lo.z = cvt_pk_bf16(f[4],  f[5]);  lo.w = cvt_pk_bf16(f[6],  f[7]);
        hi.x = cvt_pk_bf16(f[8],  f[9]);  hi.y = cvt_pk_bf16(f[10], f[11]);
        hi.z = cvt_pk_bf16(f[12], f[13]); hi.w = cvt_pk_bf16(f[14], f[15]);
        uint4* dst = (uint4*)(WT + (size_t)q * 16);
        dst[0] = lo; dst[1] = hi;
        return;
    }

    // prep_x: tile = 64 b x 64 cols (c = j*16+i); lds8[row][unit] of 8B units
    const int id = blk - 512;
    const int tb = id >> 5;
    const int tc = id & 31;
    const int b0 = tb * 64, c0 = tc * 64;

    __shared__ uint2 lds8[64][16];          // 8 KB, swizzled

    {
        const int c4 = t & 15;              // 8B unit index (4 bf16)
#pragma unroll
        for (int k = 0; k < 4; ++k) {
            const int r = (t >> 4) + 16 * k;
            const float4 f = *(const float4*)(x + (size_t)(b0 + r) * 2048 + c0 + c4 * 4);
            uint2 o;
            o.x = cvt_pk_bf16(f.x, f.y);
            o.y = cvt_pk_bf16(f.z, f.w);
            lds8[r][c4 ^ (r & 15)] = o;     // swizzled store, conflict-free
        }
    }
    __syncthreads();

    const int jb2l = t >> 5;                // 0..7 local output row
    const int jb20 = tc * 8;
#pragma unroll
    for (int h = 0; h < 2; ++h) {
        const int bl = (t & 31) + h * 32;
        const uint2 u0 = lds8[bl][(jb2l * 2)     ^ (bl & 15)];
        const uint2 u1 = lds8[bl][(jb2l * 2 + 1) ^ (bl & 15)];
        uint4 o; o.x = u0.x; o.y = u0.y; o.z = u1.x; o.w = u1.y;
        *(uint4*)(XW + ((size_t)(jb20 + jb2l) * 1024 + b0 + bl) * 8) = o;
    }
}

// ---------------------------------------------------------------------------
// kA: block = (2 n's x 64 b's), 1024 threads = 16 waves:
// wave w -> nsub = w>>3, bh = (w>>2)&1, jw = w&3 (32 j each).
// Per-block L2 traffic halves vs (1n x 32b): WT slices serve 64 b's, XW
// slices serve 2 n's; co-resident sibling waves hit L1 on shared frags.
// Phase 1: usum via 4 independent MFMA chains; 4-way jw LDS combine.
// Phase 2: batched-4 j-groups (8 loads in flight), reversed batch order for
// L1 reuse of phase-1 tail; paired full-wave logit stores.
// ---------------------------------------------------------------------------
__global__ __launch_bounds__(1024, 4)
void kA(const ushort_* __restrict__ XW, const ushort_* __restrict__ WT,
        ushort_* __restrict__ LC) {
    const int raw = blockIdx.x;                      // 256 blocks = 1/CU
    const int bid = ((raw & 7) << 5) | (raw >> 3);   // bijective XCD swizzle
    const int np  = bid >> 4;                        // 0..15 n-pair
    const int bt  = bid & 15;                        // 0..15 64-b tile
    const int t   = threadIdx.x;
    const int w   = t >> 6;                          // 0..15
    const int l   = t & 63;
    const int lo5 = l & 31;
    const int hi  = l >> 5;
    const int nsub = w >> 3;                         // 0..1
    const int bh   = (w >> 2) & 1;                   // 0..1
    const int jw   = w & 3;                          // 0..3

    const int n   = np * 2 + nsub;
    const int cb0 = bt * 64 + bh * 32;

    __shared__ float xch[16][1024];                  // 64 KB

    const ushort_* aBase = WT + ((size_t)(n * IN_N) * 32 + lo5) * 16 + (size_t)hi * 8;
    const ushort_* bBase = XW + ((size_t)hi * 1024 + cb0 + lo5) * 8;

    const int jbeg = jw * 32;

    f32x16 us0, us1, us2, us3;
#pragma unroll
    for (int r = 0; r < 16; ++r) { us0[r] = 0.f; us1[r] = 0.f; us2[r] = 0.f; us3[r] = 0.f; }

    for (int j = jbeg; j < jbeg + 32; j += 4) {
        bf16x8 a0 = *(const bf16x8*)(aBase + (size_t)j * 512);
        bf16x8 x0 = *(const bf16x8*)(bBase + (size_t)j * 16384);
        bf16x8 a1 = *(const bf16x8*)(aBase + (size_t)(j + 1) * 512);
        bf16x8 x1 = *(const bf16x8*)(bBase + (size_t)(j + 1) * 16384);
        us0 = __builtin_amdgcn_mfma_f32_32x32x16_bf16(a0, x0, us0, 0, 0, 0);
        us1 = __builtin_amdgcn_mfma_f32_32x32x16_bf16(a1, x1, us1, 0, 0, 0);
        bf16x8 a2 = *(const bf16x8*)(aBase + (size_t)(j + 2) * 512);
        bf16x8 x2 = *(const bf16x8*)(bBase + (size_t)(j + 2) * 16384);
        bf16x8 a3 = *(const bf16x8*)(aBase + (size_t)(j + 3) * 512);
        bf16x8 x3 = *(const bf16x8*)(bBase + (size_t)(j + 3) * 16384);
        us2 = __builtin_amdgcn_mfma_f32_32x32x16_bf16(a2, x2, us2, 0, 0, 0);
        us3 = __builtin_amdgcn_mfma_f32_32x32x16_bf16(a3, x3, us3, 0, 0, 0);
    }
#pragma unroll
    for (int r = 0; r < 16; ++r)
        us0[r] = (us0[r] + us1[r]) + (us2[r] + us3[r]);

    // per-lane-contiguous exchange
    {
        float4* d = (float4*)&xch[w][l * 16];
#pragma unroll
        for (int g = 0; g < 4; ++g)
            d[g] = (float4){us0[g*4], us0[g*4+1], us0[g*4+2], us0[g*4+3]};
    }
    __syncthreads();

    const int wg = w & ~3;                           // jw-group base
    f32x16 us;
#pragma unroll
    for (int g = 0; g < 4; ++g) {
        float4 s = (float4){0.f, 0.f, 0.f, 0.f};
#pragma unroll
        for (int ww = 0; ww < 4; ++ww) {
            const float4 a = *(const float4*)&xch[wg + ww][l * 16 + g * 4];
            s.x += a.x; s.y += a.y; s.z += a.z; s.w += a.w;
        }
        us[g*4] = s.x; us[g*4+1] = s.y; us[g*4+2] = s.z; us[g*4+3] = s.w;
    }

    const float rsqD = 0.17677669529663689f;  // 1/sqrt(32)
    f32x16 zc;
#pragma unroll
    for (int r = 0; r < 16; ++r) zc[r] = 0.f;

    for (int jb = jbeg + 28; jb >= jbeg; jb -= 4) {  // reversed batches: L1-hot tail
        bf16x8 a0 = *(const bf16x8*)(aBase + (size_t)jb * 512);
        bf16x8 x0 = *(const bf16x8*)(bBase + (size_t)jb * 16384);
        bf16x8 a1 = *(const bf16x8*)(aBase + (size_t)(jb + 1) * 512);
        bf16x8 x1 = *(const bf16x8*)(bBase + (size_t)(jb + 1) * 16384);
        bf16x8 a2 = *(const bf16x8*)(aBase + (size_t)(jb + 2) * 512);
        bf16x8 x2 = *(const bf16x8*)(bBase + (size_t)(jb + 2) * 16384);
        bf16x8 a3 = *(const bf16x8*)(aBase + (size_t)(jb + 3) * 512);
        bf16x8 x3 = *(const bf16x8*)(bBase + (size_t)(jb + 3) * 16384);
        f32x16 u0 = __builtin_amdgcn_mfma_f32_32x32x16_bf16(a0, x0, zc, 0, 0, 0);
        f32x16 u1 = __builtin_amdgcn_mfma_f32_32x32x16_bf16(a1, x1, zc, 0, 0, 0);
        f32x16 u2 = __builtin_amdgcn_mfma_f32_32x32x16_bf16(a2, x2, zc, 0, 0, 0);
        f32x16 u3 = __builtin_amdgcn_mfma_f32_32x32x16_bf16(a3, x3, zc, 0, 0, 0);

        float p0a = u0[0] * us[0], p0b = u0[1] * us[1];
        float p1a = u1[0] * us[0], p1b = u1[1] * us[1];
        float p2a = u2[0] * us[0], p2b = u2[1] * us[1];
        float p3a = u3[0] * us[0], p3b = u3[1] * us[1];
#pragma unroll
        for (int r = 2; r < 16; r += 2) {
            p0a = fmaf(u0[r], us[r], p0a); p0b = fmaf(u0[r + 1], us[r + 1], p0b);
            p1a = fmaf(u1[r], us[r], p1a); p1b = fmaf(u1[r + 1], us[r + 1], p1b);
            p2a = fmaf(u2[r], us[r], p2a); p2b = fmaf(u2[r + 1], us[r + 1], p2b);
            p3a = fmaf(u3[r], us[r], p3a); p3b = fmaf(u3[r + 1], us[r + 1], p3b);
        }
        float p0 = p0a + p0b, p1 = p1a + p1b, p2 = p2a + p2b, p3 = p3a + p3b;
        p0 += __shfl_xor(p0, 32);
        p1 += __shfl_xor(p1, 32);
        p2 += __shfl_xor(p2, 32);
        p3 += __shfl_xor(p3, 32);
        // paired stores: lanes 0-31 store row jb+k, lanes 32-63 row jb+k+1
        const float q01 = (hi ? p1 : p0) * rsqD;
        const float q23 = (hi ? p3 : p2) * rsqD;
        uint_ k01 = cvt_pk_bf16(q01, q01);
        uint_ k23 = cvt_pk_bf16(q23, q23);
        LC[(size_t)(n * IN_N + jb + hi) * 1024 + cb0 + lo5]     = (ushort_)(k01 & 0xffffu);
        LC[(size_t)(n * IN_N + jb + 2 + hi) * 1024 + cb0 + lo5] = (ushort_)(k23 & 0xffffu);
    }
}

// ---------------------------------------------------------------------------
// kB: softmax over n per (b,j), 1 b per thread, fully coalesced; + bias.
// ---------------------------------------------------------------------------
__global__ __launch_bounds__(256)
void kB(const float* __restrict__ bias, ushort_* __restrict__ LC) {
    const int t = blockIdx.x * 256 + threadIdx.x;   // 131072 = 128j * 1024b
    const int j = t >> 10;                           // uniform per block
    const int b = t & 1023;
    float v[NCAP];
    float m = -1e30f;
#pragma unroll
    for (int n = 0; n < NCAP; ++n) {
        v[n] = bf16_to_f(LC[(size_t)(n * IN_N + j) * 1024 + b]);
        m = fmaxf(m, v[n]);
    }
    float s = 0.f;
#pragma unroll
    for (int n = 0; n < NCAP; ++n) { v[n] = __expf(v[n] - m); s += v[n]; }
    const float inv = 1.f / s;
#pragma unroll
    for (int n = 0; n < NCAP; ++n) {
        const float c = v[n] * inv + bias[n * IN_N + j];
        uint_ pk = cvt_pk_bf16(c, c);
        LC[(size_t)(n * IN_N + j) * 1024 + b] = (ushort_)(pk & 0xffffu);
    }
}

// ---------------------------------------------------------------------------
// kC: s[b,n,z] = sum_j c*u; block (2n x 64b) x 16 waves, batched-4 j-groups,
// single s-chain; jw==0 waves do epilogue (combine + squash + store).
// ---------------------------------------------------------------------------
__global__ __launch_bounds__(1024, 4)
void kC(const ushort_* __restrict__ XW, const ushort_* __restrict__ WT,
        const ushort_* __restrict__ LC, float* __restrict__ out) {
    const int raw = blockIdx.x;
    const int bid = ((raw & 7) << 5) | (raw >> 3);
    const int np  = bid >> 4;
    const int bt  = bid & 15;
    const int t   = threadIdx.x;
    const int w   = t >> 6;
    const int l   = t & 63;
    const int lo5 = l & 31;
    const int hi  = l >> 5;
    const int nsub = w >> 3;
    const int bh   = (w >> 2) & 1;
    const int jw   = w & 3;

    const int n   = np * 2 + nsub;
    const int cb0 = bt * 64 + bh * 32;

    __shared__ float xch[16][1024];                  // 64 KB

    const ushort_* aBase = WT + ((size_t)(n * IN_N) * 32 + lo5) * 16 + (size_t)hi * 8;
    const ushort_* bBase = XW + ((size_t)hi * 1024 + cb0 + lo5) * 8;
    const ushort_* cBase = LC + (size_t)(n * IN_N) * 1024 + cb0 + lo5;

    f32x16 s0, zc;
#pragma unroll
    for (int r = 0; r < 16; ++r) { s0[r] = 0.f; zc[r] = 0.f; }

    const int jbeg = jw * 32;
    for (int jb = jbeg; jb < jbeg + 32; jb += 4) {
        bf16x8 a0 = *(const bf16x8*)(aBase + (size_t)jb * 512);
        bf16x8 x0 = *(const bf16x8*)(bBase + (size_t)jb * 16384);
        bf16x8 a1 = *(const bf16x8*)(aBase + (size_t)(jb + 1) * 512);
        bf16x8 x1 = *(const bf16x8*)(bBase + (size_t)(jb + 1) * 16384);
        bf16x8 a2 = *(const bf16x8*)(aBase + (size_t)(jb + 2) * 512);
        bf16x8 x2 = *(const bf16x8*)(bBase + (size_t)(jb + 2) * 16384);
        bf16x8 a3 = *(const bf16x8*)(aBase + (size_t)(jb + 3) * 512);
        bf16x8 x3 = *(const bf16x8*)(bBase + (size_t)(jb + 3) * 16384);
        const float c0 = bf16_to_f(cBase[(size_t)jb * 1024]);
        const float c1 = bf16_to_f(cBase[(size_t)(jb + 1) * 1024]);
        const float c2 = bf16_to_f(cBase[(size_t)(jb + 2) * 1024]);
        const float c3 = bf16_to_f(cBase[(size_t)(jb + 3) * 1024]);
        f32x16 u0 = __builtin_amdgcn_mfma_f32_32x32x16_bf16(a0, x0, zc, 0, 0, 0);
        f32x16 u1 = __builtin_amdgcn_mfma_f32_32x32x16_bf16(a1, x1, zc, 0, 0, 0);
        f32x16 u2 = __builtin_amdgcn_mfma_f32_32x32x16_bf16(a2, x2, zc, 0, 0, 0);
        f32x16 u3 = __builtin_amdgcn_mfma_f32_32x32x16_bf16(a3, x3, zc, 0, 0, 0);
#pragma unroll
        for (int r = 0; r < 16; ++r) {
            float acc = fmaf(c0, u0[r], s0[r]);
            acc = fmaf(c1, u1[r], acc);
            acc = fmaf(c2, u2[r], acc);
            s0[r] = fmaf(c3, u3[r], acc);
        }
    }

    if (jw > 0) {
        float4* d = (float4*)&xch[w][l * 16];
#pragma unroll
        for (int g = 0; g < 4; ++g)
            d[g] = (float4){s0[g*4], s0[g*4+1], s0[g*4+2], s0[g*4+3]};
    }
    __syncthreads();

    if (jw == 0) {
        const int wg = w;                            // group base (jw==0)
#pragma unroll
        for (int g = 0; g < 4; ++g) {
#pragma unroll
            for (int ww = 1; ww < 4; ++ww) {
                const float4 a = *(const float4*)&xch[wg + ww][l * 16 + g * 4];
                s0[g*4]   += a.x; s0[g*4+1] += a.y;
                s0[g*4+2] += a.z; s0[g*4+3] += a.w;
            }
        }
        float q0 = s0[0] * s0[0], q1 = s0[1] * s0[1];
        float q2 = s0[2] * s0[2], q3 = s0[3] * s0[3];
#pragma unroll
        for (int r = 4; r < 16; r += 4) {
            q0 = fmaf(s0[r],     s0[r],     q0);
            q1 = fmaf(s0[r + 1], s0[r + 1], q1);
            q2 = fmaf(s0[r + 2], s0[r + 2], q2);
            q3 = fmaf(s0[r + 3], s0[r + 3], q3);
        }
        float q = (q0 + q1) + (q2 + q3);
        q += __shfl_xor(q, 32);             // other half's 16 z's
        const float nn = sqrtf(q);
        const float f  = (1.f - 1.f / (__expf(nn) + 1e-20f)) / (nn + 1e-20f);
        // lane (lo5,hi), reg r -> z = (r&3) + 8*(r>>2) + 4*hi
        float* op = out + ((size_t)(cb0 + lo5) * NCAP + n) * DCAP + hi * 4;
#pragma unroll
        for (int g = 0; g < 4; ++g) {
            float4 v4 = { s0[g*4] * f, s0[g*4+1] * f, s0[g*4+2] * f, s0[g*4+3] * f };
            *(float4*)(op + g * 8) = v4;
        }
    }
}

// ---------------------------------------------------------------------------
extern "C" void kernel_launch(void* const* d_in, const int* in_sizes, int n_in,
                              void* d_out, int out_size, void* d_ws, size_t ws_size,
                              hipStream_t stream) {
    const float* x    = (const float*)d_in[0];   // [1024,128,16]
    const float* W    = (const float*)d_in[1];   // [32,128,16,32]
    const float* bias = (const float*)d_in[2];   // [32,128,1]
    float* out = (float*)d_out;                  // [1024,32,32]

    char* ws = (char*)d_ws;
    ushort_* XW = (ushort_*)ws;                  // 4 MB bf16 x, relaid
    ushort_* WT = (ushort_*)(ws + (4u << 20));   // 4 MB bf16 W^T
    ushort_* LC = (ushort_*)(ws + (8u << 20));   // 8 MB bf16 logits/c

    prep<<<1024, 256, 0, stream>>>(x, W, XW, WT);
    kA<<<256, 1024, 0, stream>>>(XW, WT, LC);
    kB<<<512, 256, 0, stream>>>(bias, LC);
    kC<<<256, 1024, 0, stream>>>(XW, WT, LC, out);
}